// Round 14
// baseline (306.537 us; speedup 1.0000x reference)
//
#include <hip/hip_runtime.h>
#include <hip/hip_bf16.h>

#define SEQ    1024
#define BSZW   4
#define DMODEL 1024
#define NHEAD  16
#define DHEAD  64
#define MROWS  (SEQ*BSZW)          // 4096
#define QKVN   (3*NHEAD*DHEAD)     // 3072

typedef __attribute__((ext_vector_type(8))) short short8;
typedef __attribute__((ext_vector_type(4))) short short4v;
typedef __attribute__((ext_vector_type(4))) float f32x4;

__device__ __forceinline__ float bf2f(short s) {
    union { int i; float f; } u; u.i = ((int)(unsigned short)s) << 16; return u.f;
}
__device__ __forceinline__ short f2bf(float f) {   // RNE f32->bf16
    union { float f; unsigned int u; } v; v.f = f;
    unsigned int r = v.u + 0x7FFFu + ((v.u >> 16) & 1u);
    return (short)(unsigned short)(r >> 16);
}

// async global->LDS, 16B per lane; LDS dest = wave-uniform base + lane*16
__device__ __forceinline__ void async16(const void* g, void* s) {
    __builtin_amdgcn_global_load_lds(
        (__attribute__((address_space(1))) void*)(g),
        (__attribute__((address_space(3))) void*)(s), 16, 0, 0);
}

// ---------------------------------------------------------------------------
// prep_all: z=3 -> f32->bf16 converts (w 4M elems, r 1M elems, 2048/block);
//           z=0..2 -> transpose+convert qkv_w/r_w/o_w -> [C,R] bf16
// ---------------------------------------------------------------------------
__global__ __launch_bounds__(256) void prep_all(const float* __restrict__ w,
                                                const float* __restrict__ r,
                                                const float* __restrict__ qkv_w,
                                                const float* __restrict__ r_w,
                                                const float* __restrict__ o_w,
                                                short* __restrict__ Wb,
                                                short* __restrict__ rb,
                                                short* __restrict__ QKVt,
                                                short* __restrict__ RWt,
                                                short* __restrict__ OWt)
{
    const int z = blockIdx.z;
    const int tid = threadIdx.x;
    if (z == 3) {
        size_t flat = (size_t)blockIdx.y * 96 + blockIdx.x;
        if (flat >= 2560) return;                    // 5,242,880 / 2048
        size_t idx = flat * 2048 + (size_t)tid * 8;
        const float* in = w; short* out = Wb;
        if (idx >= (size_t)4194304) { in = r; out = rb; idx -= 4194304; }
        float4 a = *(const float4*)(in + idx);
        float4 b = *(const float4*)(in + idx + 4);
        out[idx + 0] = f2bf(a.x); out[idx + 1] = f2bf(a.y);
        out[idx + 2] = f2bf(a.z); out[idx + 3] = f2bf(a.w);
        out[idx + 4] = f2bf(b.x); out[idx + 5] = f2bf(b.y);
        out[idx + 6] = f2bf(b.z); out[idx + 7] = f2bf(b.w);
        return;
    }
    const int bx = blockIdx.x, by = blockIdx.y;
    const float* in; short* out; int C;
    if (z == 0)      { in = qkv_w; out = QKVt; C = QKVN; }
    else if (z == 1) { in = r_w;   out = RWt;  C = DMODEL; if (bx >= 32) return; }
    else             { in = o_w;   out = OWt;  C = DMODEL; if (bx >= 32) return; }
    const int R = DMODEL;
    __shared__ short t[32][33];
    const int rr0 = tid >> 5, c = tid & 31;
    #pragma unroll
    for (int rr = 0; rr < 4; ++rr) {
        int rl = rr0 + rr * 8;
        t[c][rl] = f2bf(in[(size_t)(by * 32 + rl) * C + bx * 32 + c]);
    }
    __syncthreads();
    #pragma unroll
    for (int rr = 0; rr < 4; ++rr) {
        int rl = rr0 + rr * 8;
        out[(size_t)(bx * 32 + rl) * R + by * 32 + c] = t[rl][c];
    }
}

// ---------------------------------------------------------------------------
// V transpose: in bf16 [bh][j=1024][d=64] -> out bf16 [bh][d][j]
// ---------------------------------------------------------------------------
__global__ __launch_bounds__(256) void vtrans(const short* __restrict__ in,
                                              short* __restrict__ out)
{
    __shared__ short t[32][33];
    const int tid = threadIdx.x;
    const int r = tid >> 5, c = tid & 31;
    const int bx = blockIdx.x, by = blockIdx.y, bh = blockIdx.z;
    #pragma unroll
    for (int rr = 0; rr < 4; ++rr) {
        int rl = r + rr * 8;
        t[c][rl] = in[((size_t)bh * SEQ + bx * 32 + rl) * DHEAD + by * 32 + c];
    }
    __syncthreads();
    #pragma unroll
    for (int rr = 0; rr < 4; ++rr) {
        int rl = r + rr * 8;
        out[((size_t)bh * DHEAD + by * 32 + rl) * SEQ + bx * 32 + c] = t[rl][c];
    }
}

// ---------------------------------------------------------------------------
// MFMA GEMM body, 128x128 tile, BK=64, single-buffer 2-barrier with two
// compute half-steps per barrier. 8-chunk XOR swizzle.
// Wave w: rows (w&1)*64, cols (w>>1)*64.
// ---------------------------------------------------------------------------
#define GEMM_BODY_128(A_, Bt_, K_)                                             \
    __shared__ short As[128 * 64];                                              \
    __shared__ short Bs[128 * 64];                                              \
    const int w = tid >> 6, lane = tid & 63;                                    \
    const int L15 = lane & 15, quad = lane >> 4;                                \
    const int mq = (w & 1) * 64, nq = (w >> 1) * 64;                            \
    f32x4 acc[4][4];                                                            \
    _Pragma("unroll")                                                           \
    for (int i = 0; i < 4; ++i)                                                 \
        _Pragma("unroll")                                                       \
        for (int j = 0; j < 4; ++j) acc[i][j] = (f32x4){0.f, 0.f, 0.f, 0.f};    \
    const int srow  = w * 8 + (lane >> 3);         /* row within 32-grp */      \
    const int schnk = ((lane & 7) ^ (lane >> 3)) * 8;                           \
    const int rkey  = (L15 & 7);                                                \
    for (int k0 = 0; k0 < K_; k0 += 64) {                                       \
        __syncthreads();                                                        \
        _Pragma("unroll")                                                       \
        for (int s = 0; s < 4; ++s) {                                           \
            async16(A_ + (size_t)(m0 + s * 32 + srow) * K_ + k0 + schnk,        \
                    &As[(s * 32 + w * 8) * 64]);                                \
            async16(Bt_ + (size_t)(n0 + s * 32 + srow) * K_ + k0 + schnk,       \
                    &Bs[(s * 32 + w * 8) * 64]);                                \
        }                                                                       \
        __syncthreads();                                                        \
        _Pragma("unroll")                                                       \
        for (int half = 0; half < 2; ++half) {                                  \
            const int rp = ((quad + 4 * half) ^ rkey) * 8;                      \
            short8 a[4], b[4];                                                  \
            _Pragma("unroll")                                                   \
            for (int rt = 0; rt < 4; ++rt)                                      \
                a[rt] = *(const short8*)&As[(mq + rt * 16 + L15) * 64 + rp];    \
            _Pragma("unroll")                                                   \
            for (int ct = 0; ct < 4; ++ct)                                      \
                b[ct] = *(const short8*)&Bs[(nq + ct * 16 + L15) * 64 + rp];    \
            _Pragma("unroll")                                                   \
            for (int rt = 0; rt < 4; ++rt)                                      \
                _Pragma("unroll")                                               \
                for (int ct = 0; ct < 4; ++ct)                                  \
                    acc[rt][ct] = __builtin_amdgcn_mfma_f32_16x16x32_bf16(      \
                        a[rt], b[ct], acc[rt][ct], 0, 0, 0);                    \
        }                                                                       \
    }

// ---------------------------------------------------------------------------
// GEMM 1+2 fused with XCD-aware region swizzle: linear bid -> xcd = bid&7;
// qkv (bid<768): 8 regions of 8(by) x 12(bx) tiles. rk (bid>=768): 64 tiles.
// ---------------------------------------------------------------------------
__global__ __launch_bounds__(256) void qkv_rk_mfma(const short* __restrict__ Wb,
                                                   const short* __restrict__ QKVt,
                                                   const short* __restrict__ rbuf,
                                                   const short* __restrict__ RWt,
                                                   const float* __restrict__ rwb,
                                                   const float* __restrict__ rrb,
                                                   short* __restrict__ Qwb,
                                                   short* __restrict__ Qrb,
                                                   short* __restrict__ Kb,
                                                   short* __restrict__ Vb,
                                                   short* __restrict__ RK)
{
    const int tid = threadIdx.x;
    const int bid = blockIdx.y * 24 + blockIdx.x;   // linear, x fastest
    const bool isrk = (bid >= 768);
    int m0, n0;
    if (isrk) {
        int t = bid - 768;
        if (t >= 64) return;
        m0 = (t >> 3) * 128;
        n0 = (t & 7) * 128;
    } else {
        const int r = bid & 7;          // XCD (round-robin heuristic)
        const int s = bid >> 3;         // 0..95 within region
        const int by = (r >> 1) * 8 + s / 12;
        const int bx = (r & 1) * 12 + s % 12;
        m0 = by * 128;
        n0 = bx * 128;
    }
    const short* A_  = isrk ? rbuf : Wb;
    const short* Bt_ = isrk ? RWt : QKVt;
    GEMM_BODY_128(A_, Bt_, 1024)

    if (isrk) {
        const int h = (n0 + nq) >> 6;
        #pragma unroll
        for (int rt = 0; rt < 4; ++rt)
            #pragma unroll
            for (int g = 0; g < 4; ++g) {
                int m = m0 + mq + rt * 16 + quad * 4 + g;
                #pragma unroll
                for (int ct = 0; ct < 4; ++ct)
                    RK[((size_t)h * SEQ + m) * DHEAD + ct * 16 + L15] =
                        f2bf(acc[rt][ct][g]);
            }
        return;
    }
    const int nb = n0 + nq;
    const int chunk = nb >> 10;
    const int h = (nb >> 6) & 15;
    float rw4[4], rr4[4];
    if (chunk == 0) {
        #pragma unroll
        for (int ct = 0; ct < 4; ++ct) {
            rw4[ct] = rwb[h * DHEAD + ct * 16 + L15];
            rr4[ct] = rrb[h * DHEAD + ct * 16 + L15];
        }
    }
    #pragma unroll
    for (int rt = 0; rt < 4; ++rt)
        #pragma unroll
        for (int g = 0; g < 4; ++g) {
            int m = m0 + mq + rt * 16 + quad * 4 + g;
            int qi = m >> 2, b = m & 3;
            size_t rowbase = ((size_t)(b * NHEAD + h) * SEQ + qi) * DHEAD;
            #pragma unroll
            for (int ct = 0; ct < 4; ++ct) {
                int d = ct * 16 + L15;
                float v = acc[rt][ct][g];
                if (chunk == 0) {
                    Qwb[rowbase + d] = f2bf(v + rw4[ct]);
                    Qrb[rowbase + d] = f2bf(v + rr4[ct]);
                } else if (chunk == 1) {
                    Kb[rowbase + d] = f2bf(v);
                } else {
                    Vb[rowbase + d] = f2bf(v);
                }
            }
        }
}

// ---------------------------------------------------------------------------
// GEMM 3: ATTb[4096,1024] @ OWt[1024,1024]^T -> AO bf16. 128x64 tile,
// BK=64 (24KB LDS), XCD region swizzle (8 regions of 8(m) x 8(n) tiles).
// ---------------------------------------------------------------------------
__global__ __launch_bounds__(256) void oproj_mfma(const short* __restrict__ A,
                                                  const short* __restrict__ Bt,
                                                  short* __restrict__ C)
{
    __shared__ short As[128 * 64];
    __shared__ short Bs[64 * 64];
    const int tid = threadIdx.x;
    const int w = tid >> 6, lane = tid & 63;
    const int L15 = lane & 15, quad = lane >> 4;
    const int bid = blockIdx.y * 16 + blockIdx.x;
    const int rg = bid & 7, s = bid >> 3;          // region / index in region
    const int m0 = ((rg >> 1) * 8 + s / 8) * 128;
    const int n0 = ((rg & 1) * 8 + s % 8) * 64;
    const int mq = w * 32;
    f32x4 acc[2][4];
    #pragma unroll
    for (int i = 0; i < 2; ++i)
        #pragma unroll
        for (int j = 0; j < 4; ++j) acc[i][j] = (f32x4){0.f, 0.f, 0.f, 0.f};
    const int srow  = w * 8 + (lane >> 3);
    const int schnk = ((lane & 7) ^ (lane >> 3)) * 8;
    const int rkey  = (L15 & 7);
    for (int k0 = 0; k0 < 1024; k0 += 64) {
        __syncthreads();
        #pragma unroll
        for (int s2 = 0; s2 < 4; ++s2)
            async16(A + (size_t)(m0 + s2 * 32 + srow) * 1024 + k0 + schnk,
                    &As[(s2 * 32 + w * 8) * 64]);
        #pragma unroll
        for (int s2 = 0; s2 < 2; ++s2)
            async16(Bt + (size_t)(n0 + s2 * 32 + srow) * 1024 + k0 + schnk,
                    &Bs[(s2 * 32 + w * 8) * 64]);
        __syncthreads();
        #pragma unroll
        for (int half = 0; half < 2; ++half) {
            const int rp = ((quad + 4 * half) ^ rkey) * 8;
            short8 a[2], b[4];
            #pragma unroll
            for (int rt = 0; rt < 2; ++rt)
                a[rt] = *(const short8*)&As[(mq + rt * 16 + L15) * 64 + rp];
            #pragma unroll
            for (int ct = 0; ct < 4; ++ct)
                b[ct] = *(const short8*)&Bs[(ct * 16 + L15) * 64 + rp];
            #pragma unroll
            for (int rt = 0; rt < 2; ++rt)
                #pragma unroll
                for (int ct = 0; ct < 4; ++ct)
                    acc[rt][ct] = __builtin_amdgcn_mfma_f32_16x16x32_bf16(
                        a[rt], b[ct], acc[rt][ct], 0, 0, 0);
        }
    }
    #pragma unroll
    for (int rt = 0; rt < 2; ++rt)
        #pragma unroll
        for (int g = 0; g < 4; ++g) {
            int m = m0 + mq + rt * 16 + quad * 4 + g;
            #pragma unroll
            for (int ct = 0; ct < 4; ++ct)
                C[(size_t)m * DMODEL + n0 + ct * 16 + L15] = f2bf(acc[rt][ct][g]);
        }
}

// ---------------------------------------------------------------------------
// MFMA flash attention v9: paired q-tiles processed CONCURRENTLY.
// Block (bh, itA): tiles itA (0..7) and itB=15-itA share each staged K/V
// j-tile; B computes every jt=0..itB, A joins while jt<=itA. Two Pbufs give
// two independent MFMA/gather chains per wave (ILP). 17 tile-computations
// per block (uniform), avg 12.5 stages (was 17). Static-max exp2 softmax,
// MFMA row-sum, per-tile index math identical to the verified R13 kernel.
// ---------------------------------------------------------------------------
__global__ __launch_bounds__(256) void attn_mfma(const short* __restrict__ Qw,
                                                 const short* __restrict__ Qr,
                                                 const short* __restrict__ Kg,
                                                 const short* __restrict__ Vt,
                                                 const short* __restrict__ RK,
                                                 short* __restrict__ ATT)
{
    __shared__ short Ks[2][64 * 64];       // 16KB
    __shared__ short Vts[2][64 * 64];      // 16KB
    __shared__ short PbA[4][16][88];       // 11KB window+prob scratch, tile A
    __shared__ short PbB[4][16][88];       // 11KB, tile B

    const int tid  = threadIdx.x;
    const int w    = tid >> 6;
    const int lane = tid & 63;
    const int L15  = lane & 15;
    const int quad = lane >> 4;
    const int bh   = blockIdx.x;
    const int itA  = blockIdx.y;               // 0..7
    const int itB  = 15 - itA;                 // 15..8
    const int h    = bh & (NHEAD - 1);
    const int b    = bh >> 4;
    const float c1 = 0.1803368801f;            // 0.125 * log2(e)

    const short* Kbh = Kg + (size_t)bh * SEQ * DHEAD;
    const short* Vbh = Vt + (size_t)bh * DHEAD * SEQ;
    const short* Rh  = RK + (size_t)h * SEQ * DHEAD;

    const int srow  = w * 8 + (lane >> 3);
    const int schnk = ((lane & 7) ^ (lane >> 3)) * 8;
    const int rp0 = ((quad)     ^ (L15 & 7)) * 8;
    const int rp1 = ((quad + 4) ^ (L15 & 7)) * 8;

    short8 vone;
    #pragma unroll
    for (int i = 0; i < 8; ++i) vone[i] = (short)0x3F80;   // bf16 1.0

    // persistent Q fragments for both tiles (A-operand layout)
    short8 qwfA[2], qrfA[2], qwfB[2], qrfB[2];
    {
        const short* qb = Qw + ((size_t)bh * SEQ + itA * 64 + w * 16 + L15) * DHEAD + quad * 8;
        qwfA[0] = *(const short8*)qb;
        qwfA[1] = *(const short8*)(qb + 32);
        const short* qc = Qr + ((size_t)bh * SEQ + itA * 64 + w * 16 + L15) * DHEAD + quad * 8;
        qrfA[0] = *(const short8*)qc;
        qrfA[1] = *(const short8*)(qc + 32);
        const short* qb2 = Qw + ((size_t)bh * SEQ + itB * 64 + w * 16 + L15) * DHEAD + quad * 8;
        qwfB[0] = *(const short8*)qb2;
        qwfB[1] = *(const short8*)(qb2 + 32);
        const short* qc2 = Qr + ((size_t)bh * SEQ + itB * 64 + w * 16 + L15) * DHEAD + quad * 8;
        qrfB[0] = *(const short8*)qc2;
        qrfB[1] = *(const short8*)(qc2 + 32);
    }

    f32x4 OA[4], OB[4], OlA, OlB;
    #pragma unroll
    for (int c = 0; c < 4; ++c) {
        OA[c] = (f32x4){0.f, 0.f, 0.f, 0.f};
        OB[c] = (f32x4){0.f, 0.f, 0.f, 0.f};
    }
    OlA = (f32x4){0.f, 0.f, 0.f, 0.f};
    OlB = (f32x4){0.f, 0.f, 0.f, 0.f};

    // preload stage jt=0 into buf 0
    #pragma unroll
    for (int q = 0; q < 2; ++q) {
        int rr = q * 32 + srow;
        async16(Kbh + (size_t)rr * DHEAD + schnk, &Ks[0][(q * 32 + w * 8) * 64]);
        async16(Vbh + (size_t)rr * SEQ + schnk,   &Vts[0][(q * 32 + w * 8) * 64]);
    }

    for (int jt = 0; jt <= itB; ++jt) {
        const int buf  = jt & 1;
        const int j0   = jt * 64;
        const bool actA = (jt <= itA);

        __syncthreads();   // stage(jt) landed; buf^1 free

        if (jt < itB) {
            const int j0n = j0 + 64;
            #pragma unroll
            for (int q = 0; q < 2; ++q) {
                int rr = q * 32 + srow;
                async16(Kbh + (size_t)(j0n + rr) * DHEAD + schnk,
                        &Ks[buf ^ 1][(q * 32 + w * 8) * 64]);
                async16(Vbh + (size_t)rr * SEQ + j0n + schnk,
                        &Vts[buf ^ 1][(q * 32 + w * 8) * 64]);
            }
        }

        // ---- AC for both tiles from the shared staged K tile ----
        f32x4 SA[4], SB[4];
        #pragma unroll
        for (int ct = 0; ct < 4; ++ct) {
            short8 b0 = *(const short8*)&Ks[buf][(ct * 16 + L15) * 64 + rp0];
            short8 b1 = *(const short8*)&Ks[buf][(ct * 16 + L15) * 64 + rp1];
            f32x4 aB = (f32x4){0.f, 0.f, 0.f, 0.f};
            aB = __builtin_amdgcn_mfma_f32_16x16x32_bf16(qwfB[0], b0, aB, 0, 0, 0);
            aB = __builtin_amdgcn_mfma_f32_16x16x32_bf16(qwfB[1], b1, aB, 0, 0, 0);
            SB[ct] = aB;
            if (actA) {
                f32x4 aA = (f32x4){0.f, 0.f, 0.f, 0.f};
                aA = __builtin_amdgcn_mfma_f32_16x16x32_bf16(qwfA[0], b0, aA, 0, 0, 0);
                aA = __builtin_amdgcn_mfma_f32_16x16x32_bf16(qwfA[1], b1, aA, 0, 0, 0);
                SA[ct] = aA;
            }
        }

        // ---- BD window matmuls (B always; A if active) ----
        {
            const int rel0B = 960 + 64 * (jt - itB);
            #pragma unroll
            for (int cp = 0; cp < 5; ++cp) {
                int ct  = (3 - w) + cp;
                int rel = rel0B + ct * 16 + L15;
                rel = (rel > SEQ - 1) ? (SEQ - 1) : rel;
                rel = (rel < 0) ? 0 : rel;
                const short* rp = Rh + (size_t)rel * DHEAD + quad * 8;
                short8 r0 = *(const short8*)rp;
                short8 r1 = *(const short8*)(rp + 32);
                f32x4 p = (f32x4){0.f, 0.f, 0.f, 0.f};
                p = __builtin_amdgcn_mfma_f32_16x16x32_bf16(qrfB[0], r0, p, 0, 0, 0);
                p = __builtin_amdgcn_mfma_f32_16x16x32_bf16(qrfB[1], r1, p, 0, 0, 0);
                #pragma unroll
                for (int g = 0; g < 4; ++g)
                    PbB[w][quad * 4 + g][cp * 16 + L15] = f2bf(p[g]);
            }
        }
        if (actA) {
            const int rel0A = 960 + 64 * (jt - itA);
            #pragma unroll
            for (int cp = 0; cp < 5; ++cp) {
                int ct  = (3 - w) + cp;
                int rel = rel0A + ct * 16 + L15;
                rel = (rel > SEQ - 1) ? (SEQ - 1) : rel;
                rel = (rel < 0) ? 0 : rel;
                const short* rp = Rh + (size_t)rel * DHEAD + quad * 8;
                short8 r0 = *(const short8*)rp;
                short8 r1 = *(const short8*)(rp + 32);
                f32x4 p = (f32x4){0.f, 0.f, 0.f, 0.f};
                p = __builtin_amdgcn_mfma_f32_16x16x32_bf16(qrfA[0], r0, p, 0, 0, 0);
                p = __builtin_amdgcn_mfma_f32_16x16x32_bf16(qrfA[1], r1, p, 0, 0, 0);
                #pragma unroll
                for (int g = 0; g < 4; ++g)
                    PbA[w][quad * 4 + g][cp * 16 + L15] = f2bf(p[g]);
            }
        }

        // ---- gather rel-shift at t = ct*16 + L15 - r + 15; mask; exp2 ----
        #pragma unroll
        for (int ct = 0; ct < 4; ++ct)
            #pragma unroll
            for (int g = 0; g < 4; ++g) {
                int r = quad * 4 + g;
                int t = ct * 16 + L15 - r + 15;
                SB[ct][g] += bf2f(PbB[w][r][t]);
                if (actA) SA[ct][g] += bf2f(PbA[w][r][t]);
            }
        if (jt == itB) {
            #pragma unroll
            for (int ct = 0; ct < 4; ++ct)
                #pragma unroll
                for (int g = 0; g < 4; ++g) {
                    int i = itB * 64 + w * 16 + quad * 4 + g;
                    int j = j0 + ct * 16 + L15;
                    if (j > i) SB[ct][g] = -1e30f;
                }
        }
        if (jt == itA) {
            #pragma unroll
            for (int ct = 0; ct < 4; ++ct)
                #pragma unroll
                for (int g = 0; g < 4; ++g) {
                    int i = itA * 64 + w * 16 + quad * 4 + g;
                    int j = j0 + ct * 16 + L15;
                    if (j > i) SA[ct][g] = -1e30f;
                }
        }

        #pragma unroll
        for (int ct = 0; ct < 4; ++ct)
            #pragma unroll
            for (int g = 0; g < 4; ++g) {
                PbB[w][quad * 4 + g][ct * 16 + L15] =
                    f2bf(__builtin_amdgcn_exp2f(SB[ct][g] * c1));
                if (actA)
                    PbA[w][quad * 4 + g][ct * 16 + L15] =
                        f2bf(__builtin_amdgcn_exp2f(SA[ct][g] * c1));
            }
        short8 pB0 = *(const short8*)&PbB[w][L15][quad * 8];
        short8 pB1 = *(const short8*)&PbB[w][L15][32 + quad * 8];
        short8 pA0, pA1;
        if (actA) {
            pA0 = *(const short8*)&PbA[w][L15][quad * 8];
            pA1 = *(const short8*)&PbA[w][L15][32 + quad * 8];
        }

        // ---- O += P . V ;  l += P . 1  (shared staged V tile) ----
        #pragma unroll
        for (int ct = 0; ct < 4; ++ct) {
            short8 v0 = *(const short8*)&Vts[buf][(ct * 16 + L15) * 64 + rp0];
            short8 v1 = *(const short8*)&Vts[buf][(ct * 16 + L15) * 64 + rp1];
            OB[ct] = __builtin_amdgcn_mfma_f32_16x16x32_bf16(pB0, v0, OB[ct], 0, 0, 0);
            OB[ct] = __builtin_amdgcn_mfma_f32_16x16x32_bf16(pB1, v1, OB[ct], 0, 0, 0);
            if (actA) {
                OA[ct] = __builtin_amdgcn_mfma_f32_16x16x32_bf16(pA0, v0, OA[ct], 0, 0, 0);
                OA[ct] = __builtin_amdgcn_mfma_f32_16x16x32_bf16(pA1, v1, OA[ct], 0, 0, 0);
            }
        }
        OlB = __builtin_amdgcn_mfma_f32_16x16x32_bf16(pB0, vone, OlB, 0, 0, 0);
        OlB = __builtin_amdgcn_mfma_f32_16x16x32_bf16(pB1, vone, OlB, 0, 0, 0);
        if (actA) {
            OlA = __builtin_amdgcn_mfma_f32_16x16x32_bf16(pA0, vone, OlA, 0, 0, 0);
            OlA = __builtin_amdgcn_mfma_f32_16x16x32_bf16(pA1, vone, OlA, 0, 0, 0);
        }
    }

    // ---- epilogues ----
    #pragma unroll
    for (int g = 0; g < 4; ++g) {
        float invA = 1.0f / OlA[g];
        float invB = 1.0f / OlB[g];
        int iA = itA * 64 + w * 16 + quad * 4 + g;
        int iB = itB * 64 + w * 16 + quad * 4 + g;
        #pragma unroll
        for (int ct = 0; ct < 4; ++ct) {
            ATT[((size_t)iA * BSZW + b) * DMODEL + h * DHEAD + ct * 16 + L15] =
                f2bf(OA[ct][g] * invA);
            ATT[((size_t)iB * BSZW + b) * DMODEL + h * DHEAD + ct * 16 + L15] =
                f2bf(OB[ct][g] * invB);
        }
    }
}

// ---------------------------------------------------------------------------
// Residual + LayerNorm -> f32 out. One block per row; AO read as bf16.
// ---------------------------------------------------------------------------
__global__ __launch_bounds__(256) void ln_kernel(const float* __restrict__ w,
                                                 const short* __restrict__ AOb,
                                                 const float* __restrict__ g,
                                                 const float* __restrict__ bb,
                                                 float* __restrict__ out)
{
    __shared__ float red[256];
    __shared__ float sh_mu, sh_rs;
    const int m = blockIdx.x;
    const int tid = threadIdx.x;
    const int j0 = tid * 4;
    float4 xw = *(const float4*)(w + (size_t)m * DMODEL + j0);
    short4v xa = *(const short4v*)(AOb + (size_t)m * DMODEL + j0);
    float x[4] = {xw.x + bf2f(xa[0]), xw.y + bf2f(xa[1]),
                  xw.z + bf2f(xa[2]), xw.w + bf2f(xa[3])};
    red[tid] = x[0] + x[1] + x[2] + x[3];
    __syncthreads();
    for (int st = 128; st > 0; st >>= 1) {
        if (tid < st) red[tid] += red[tid + st];
        __syncthreads();
    }
    if (tid == 0) sh_mu = red[0] * (1.0f / DMODEL);
    __syncthreads();
    const float mu = sh_mu;
    float v = 0.0f;
    #pragma unroll
    for (int k = 0; k < 4; ++k) { float d = x[k] - mu; v += d * d; }
    red[tid] = v;
    __syncthreads();
    for (int st = 128; st > 0; st >>= 1) {
        if (tid < st) red[tid] += red[tid + st];
        __syncthreads();
    }
    if (tid == 0) sh_rs = rsqrtf(red[0] * (1.0f / DMODEL) + 1e-5f);
    __syncthreads();
    const float rs = sh_rs;
    float4 g4 = *(const float4*)(g + j0);
    float4 b4 = *(const float4*)(bb + j0);
    float4 o4;
    o4.x = (x[0] - mu) * rs * g4.x + b4.x;
    o4.y = (x[1] - mu) * rs * g4.y + b4.y;
    o4.z = (x[2] - mu) * rs * g4.z + b4.z;
    o4.w = (x[3] - mu) * rs * g4.w + b4.w;
    *(float4*)(out + (size_t)m * DMODEL + j0) = o4;
}

extern "C" void kernel_launch(void* const* d_in, const int* in_sizes, int n_in,
                              void* d_out, int out_size, void* d_ws, size_t ws_size,
                              hipStream_t stream)
{
    (void)in_sizes; (void)n_in; (void)out_size; (void)ws_size;
    const float* w     = (const float*)d_in[0];
    const float* r     = (const float*)d_in[1];
    // d_in[2] attn_mask: causal triu(k=1), hardcoded in attn_mfma
    const float* qkv_w = (const float*)d_in[3];
    const float* r_w   = (const float*)d_in[4];
    const float* o_w   = (const float*)d_in[5];
    const float* rrb   = (const float*)d_in[6];  // r_r_bias (BD path)
    const float* rwb   = (const float*)d_in[7];  // r_w_bias (AC path)
    const float* ln_g  = (const float*)d_in[8];
    const float* ln_b  = (const float*)d_in[9];
    float* out = (float*)d_out;

    const size_t M1 = 1024 * 1024;
    short* Wb   = (short*)d_ws;        // 4M shorts
    short* QKVt = Wb   + 4 * M1;       // 3M
    short* rb   = QKVt + 3 * M1;       // 1M
    short* RWt  = rb   + 1 * M1;       // 1M
    short* OWt  = RWt  + 1 * M1;       // 1M
    short* Qwb  = OWt  + 1 * M1;       // 4M
    short* Qrb  = Qwb  + 4 * M1;       // 4M
    short* Kb   = Qrb  + 4 * M1;       // 4M
    short* Vb   = Kb   + 4 * M1;       // 4M
    short* Vtb  = Vb   + 4 * M1;       // 4M
    short* RKb  = Vtb  + 4 * M1;       // 1M   -> total 31M shorts = 62 MB
    short* ATTb = Vb;                  // alias: Vb dead after vtrans
    short* AOb  = Kb;                  // alias: Kb dead after attn_mfma

    prep_all<<<dim3(QKVN / 32, DMODEL / 32, 4), 256, 0, stream>>>(
        w, r, qkv_w, r_w, o_w, Wb, rb, QKVt, RWt, OWt);

    qkv_rk_mfma<<<dim3(24, 35), 256, 0, stream>>>(Wb, QKVt, rb, RWt,
                                                  rwb, rrb,
                                                  Qwb, Qrb, Kb, Vb, RKb);
    vtrans<<<dim3(SEQ / 32, DHEAD / 32, BSZW * NHEAD), 256, 0, stream>>>(Vb, Vtb);
    attn_mfma<<<dim3(BSZW * NHEAD, 8), 256, 0, stream>>>(Qwb, Qrb, Kb, Vtb, RKb, ATTb);
    oproj_mfma<<<dim3(16, 32), 256, 0, stream>>>(ATTb, OWt, AOb);
    ln_kernel<<<MROWS, 256, 0, stream>>>(w, AOb, ln_g, ln_b, out);
}

// Round 15
// 231.381 us; speedup vs baseline: 1.3248x; 1.3248x over previous
//
#include <hip/hip_runtime.h>
#include <hip/hip_bf16.h>

#define SEQ    1024
#define BSZW   4
#define DMODEL 1024
#define NHEAD  16
#define DHEAD  64
#define MROWS  (SEQ*BSZW)          // 4096
#define QKVN   (3*NHEAD*DHEAD)     // 3072

typedef __attribute__((ext_vector_type(8))) short short8;
typedef __attribute__((ext_vector_type(4))) short short4v;
typedef __attribute__((ext_vector_type(4))) float f32x4;

__device__ __forceinline__ float bf2f(short s) {
    union { int i; float f; } u; u.i = ((int)(unsigned short)s) << 16; return u.f;
}
__device__ __forceinline__ short f2bf(float f) {   // RNE f32->bf16
    union { float f; unsigned int u; } v; v.f = f;
    unsigned int r = v.u + 0x7FFFu + ((v.u >> 16) & 1u);
    return (short)(unsigned short)(r >> 16);
}

// async global->LDS, 16B per lane; LDS dest = wave-uniform base + lane*16
__device__ __forceinline__ void async16(const void* g, void* s) {
    __builtin_amdgcn_global_load_lds(
        (__attribute__((address_space(1))) void*)(g),
        (__attribute__((address_space(3))) void*)(s), 16, 0, 0);
}

// ---------------------------------------------------------------------------
// prep_all: z=3 -> f32->bf16 converts (w 4M elems, r 1M elems, 2048/block);
//           z=0..2 -> transpose+convert qkv_w/r_w/o_w -> [C,R] bf16
// ---------------------------------------------------------------------------
__global__ __launch_bounds__(256) void prep_all(const float* __restrict__ w,
                                                const float* __restrict__ r,
                                                const float* __restrict__ qkv_w,
                                                const float* __restrict__ r_w,
                                                const float* __restrict__ o_w,
                                                short* __restrict__ Wb,
                                                short* __restrict__ rb,
                                                short* __restrict__ QKVt,
                                                short* __restrict__ RWt,
                                                short* __restrict__ OWt)
{
    const int z = blockIdx.z;
    const int tid = threadIdx.x;
    if (z == 3) {
        size_t flat = (size_t)blockIdx.y * 96 + blockIdx.x;
        if (flat >= 2560) return;                    // 5,242,880 / 2048
        size_t idx = flat * 2048 + (size_t)tid * 8;
        const float* in = w; short* out = Wb;
        if (idx >= (size_t)4194304) { in = r; out = rb; idx -= 4194304; }
        float4 a = *(const float4*)(in + idx);
        float4 b = *(const float4*)(in + idx + 4);
        out[idx + 0] = f2bf(a.x); out[idx + 1] = f2bf(a.y);
        out[idx + 2] = f2bf(a.z); out[idx + 3] = f2bf(a.w);
        out[idx + 4] = f2bf(b.x); out[idx + 5] = f2bf(b.y);
        out[idx + 6] = f2bf(b.z); out[idx + 7] = f2bf(b.w);
        return;
    }
    const int bx = blockIdx.x, by = blockIdx.y;
    const float* in; short* out; int C;
    if (z == 0)      { in = qkv_w; out = QKVt; C = QKVN; }
    else if (z == 1) { in = r_w;   out = RWt;  C = DMODEL; if (bx >= 32) return; }
    else             { in = o_w;   out = OWt;  C = DMODEL; if (bx >= 32) return; }
    const int R = DMODEL;
    __shared__ short t[32][33];
    const int rr0 = tid >> 5, c = tid & 31;
    #pragma unroll
    for (int rr = 0; rr < 4; ++rr) {
        int rl = rr0 + rr * 8;
        t[c][rl] = f2bf(in[(size_t)(by * 32 + rl) * C + bx * 32 + c]);
    }
    __syncthreads();
    #pragma unroll
    for (int rr = 0; rr < 4; ++rr) {
        int rl = rr0 + rr * 8;
        out[(size_t)(bx * 32 + rl) * R + by * 32 + c] = t[rl][c];
    }
}

// ---------------------------------------------------------------------------
// V transpose: in bf16 [bh][j=1024][d=64] -> out bf16 [bh][d][j]
// ---------------------------------------------------------------------------
__global__ __launch_bounds__(256) void vtrans(const short* __restrict__ in,
                                              short* __restrict__ out)
{
    __shared__ short t[32][33];
    const int tid = threadIdx.x;
    const int r = tid >> 5, c = tid & 31;
    const int bx = blockIdx.x, by = blockIdx.y, bh = blockIdx.z;
    #pragma unroll
    for (int rr = 0; rr < 4; ++rr) {
        int rl = r + rr * 8;
        t[c][rl] = in[((size_t)bh * SEQ + bx * 32 + rl) * DHEAD + by * 32 + c];
    }
    __syncthreads();
    #pragma unroll
    for (int rr = 0; rr < 4; ++rr) {
        int rl = r + rr * 8;
        out[((size_t)bh * DHEAD + by * 32 + rl) * SEQ + bx * 32 + c] = t[rl][c];
    }
}

// ---------------------------------------------------------------------------
// MFMA GEMM body, 128x128 tile, BK=64, single-buffer 2-barrier with two
// compute half-steps per barrier. 8-chunk XOR swizzle.
// Wave w: rows (w&1)*64, cols (w>>1)*64.
// ---------------------------------------------------------------------------
#define GEMM_BODY_128(A_, Bt_, K_)                                             \
    __shared__ short As[128 * 64];                                              \
    __shared__ short Bs[128 * 64];                                              \
    const int w = tid >> 6, lane = tid & 63;                                    \
    const int L15 = lane & 15, quad = lane >> 4;                                \
    const int mq = (w & 1) * 64, nq = (w >> 1) * 64;                            \
    f32x4 acc[4][4];                                                            \
    _Pragma("unroll")                                                           \
    for (int i = 0; i < 4; ++i)                                                 \
        _Pragma("unroll")                                                       \
        for (int j = 0; j < 4; ++j) acc[i][j] = (f32x4){0.f, 0.f, 0.f, 0.f};    \
    const int srow  = w * 8 + (lane >> 3);         /* row within 32-grp */      \
    const int schnk = ((lane & 7) ^ (lane >> 3)) * 8;                           \
    const int rkey  = (L15 & 7);                                                \
    for (int k0 = 0; k0 < K_; k0 += 64) {                                       \
        __syncthreads();                                                        \
        _Pragma("unroll")                                                       \
        for (int s = 0; s < 4; ++s) {                                           \
            async16(A_ + (size_t)(m0 + s * 32 + srow) * K_ + k0 + schnk,        \
                    &As[(s * 32 + w * 8) * 64]);                                \
            async16(Bt_ + (size_t)(n0 + s * 32 + srow) * K_ + k0 + schnk,       \
                    &Bs[(s * 32 + w * 8) * 64]);                                \
        }                                                                       \
        __syncthreads();                                                        \
        _Pragma("unroll")                                                       \
        for (int half = 0; half < 2; ++half) {                                  \
            const int rp = ((quad + 4 * half) ^ rkey) * 8;                      \
            short8 a[4], b[4];                                                  \
            _Pragma("unroll")                                                   \
            for (int rt = 0; rt < 4; ++rt)                                      \
                a[rt] = *(const short8*)&As[(mq + rt * 16 + L15) * 64 + rp];    \
            _Pragma("unroll")                                                   \
            for (int ct = 0; ct < 4; ++ct)                                      \
                b[ct] = *(const short8*)&Bs[(nq + ct * 16 + L15) * 64 + rp];    \
            _Pragma("unroll")                                                   \
            for (int rt = 0; rt < 4; ++rt)                                      \
                _Pragma("unroll")                                               \
                for (int ct = 0; ct < 4; ++ct)                                  \
                    acc[rt][ct] = __builtin_amdgcn_mfma_f32_16x16x32_bf16(      \
                        a[rt], b[ct], acc[rt][ct], 0, 0, 0);                    \
        }                                                                       \
    }

// ---------------------------------------------------------------------------
// GEMM 1+2 fused with XCD-aware region swizzle: linear bid -> xcd = bid&7;
// qkv (bid<768): 8 regions of 8(by) x 12(bx) tiles. rk (bid>=768): 64 tiles.
// ---------------------------------------------------------------------------
__global__ __launch_bounds__(256) void qkv_rk_mfma(const short* __restrict__ Wb,
                                                   const short* __restrict__ QKVt,
                                                   const short* __restrict__ rbuf,
                                                   const short* __restrict__ RWt,
                                                   const float* __restrict__ rwb,
                                                   const float* __restrict__ rrb,
                                                   short* __restrict__ Qwb,
                                                   short* __restrict__ Qrb,
                                                   short* __restrict__ Kb,
                                                   short* __restrict__ Vb,
                                                   short* __restrict__ RK)
{
    const int tid = threadIdx.x;
    const int bid = blockIdx.y * 24 + blockIdx.x;   // linear, x fastest
    const bool isrk = (bid >= 768);
    int m0, n0;
    if (isrk) {
        int t = bid - 768;
        if (t >= 64) return;
        m0 = (t >> 3) * 128;
        n0 = (t & 7) * 128;
    } else {
        const int r = bid & 7;          // XCD (round-robin heuristic)
        const int s = bid >> 3;         // 0..95 within region
        const int by = (r >> 1) * 8 + s / 12;
        const int bx = (r & 1) * 12 + s % 12;
        m0 = by * 128;
        n0 = bx * 128;
    }
    const short* A_  = isrk ? rbuf : Wb;
    const short* Bt_ = isrk ? RWt : QKVt;
    GEMM_BODY_128(A_, Bt_, 1024)

    if (isrk) {
        const int h = (n0 + nq) >> 6;
        #pragma unroll
        for (int rt = 0; rt < 4; ++rt)
            #pragma unroll
            for (int g = 0; g < 4; ++g) {
                int m = m0 + mq + rt * 16 + quad * 4 + g;
                #pragma unroll
                for (int ct = 0; ct < 4; ++ct)
                    RK[((size_t)h * SEQ + m) * DHEAD + ct * 16 + L15] =
                        f2bf(acc[rt][ct][g]);
            }
        return;
    }
    const int nb = n0 + nq;
    const int chunk = nb >> 10;
    const int h = (nb >> 6) & 15;
    float rw4[4], rr4[4];
    if (chunk == 0) {
        #pragma unroll
        for (int ct = 0; ct < 4; ++ct) {
            rw4[ct] = rwb[h * DHEAD + ct * 16 + L15];
            rr4[ct] = rrb[h * DHEAD + ct * 16 + L15];
        }
    }
    #pragma unroll
    for (int rt = 0; rt < 4; ++rt)
        #pragma unroll
        for (int g = 0; g < 4; ++g) {
            int m = m0 + mq + rt * 16 + quad * 4 + g;
            int qi = m >> 2, b = m & 3;
            size_t rowbase = ((size_t)(b * NHEAD + h) * SEQ + qi) * DHEAD;
            #pragma unroll
            for (int ct = 0; ct < 4; ++ct) {
                int d = ct * 16 + L15;
                float v = acc[rt][ct][g];
                if (chunk == 0) {
                    Qwb[rowbase + d] = f2bf(v + rw4[ct]);
                    Qrb[rowbase + d] = f2bf(v + rr4[ct]);
                } else if (chunk == 1) {
                    Kb[rowbase + d] = f2bf(v);
                } else {
                    Vb[rowbase + d] = f2bf(v);
                }
            }
        }
}

// ---------------------------------------------------------------------------
// GEMM 3: ATTb[4096,1024] @ OWt[1024,1024]^T -> AO bf16. 128x64 tile,
// BK=64 (24KB LDS), XCD region swizzle (8 regions of 8(m) x 8(n) tiles).
// ---------------------------------------------------------------------------
__global__ __launch_bounds__(256) void oproj_mfma(const short* __restrict__ A,
                                                  const short* __restrict__ Bt,
                                                  short* __restrict__ C)
{
    __shared__ short As[128 * 64];
    __shared__ short Bs[64 * 64];
    const int tid = threadIdx.x;
    const int w = tid >> 6, lane = tid & 63;
    const int L15 = lane & 15, quad = lane >> 4;
    const int bid = blockIdx.y * 16 + blockIdx.x;
    const int rg = bid & 7, s = bid >> 3;          // region / index in region
    const int m0 = ((rg >> 1) * 8 + s / 8) * 128;
    const int n0 = ((rg & 1) * 8 + s % 8) * 64;
    const int mq = w * 32;
    f32x4 acc[2][4];
    #pragma unroll
    for (int i = 0; i < 2; ++i)
        #pragma unroll
        for (int j = 0; j < 4; ++j) acc[i][j] = (f32x4){0.f, 0.f, 0.f, 0.f};
    const int srow  = w * 8 + (lane >> 3);
    const int schnk = ((lane & 7) ^ (lane >> 3)) * 8;
    const int rkey  = (L15 & 7);
    for (int k0 = 0; k0 < 1024; k0 += 64) {
        __syncthreads();
        #pragma unroll
        for (int s2 = 0; s2 < 4; ++s2)
            async16(A + (size_t)(m0 + s2 * 32 + srow) * 1024 + k0 + schnk,
                    &As[(s2 * 32 + w * 8) * 64]);
        #pragma unroll
        for (int s2 = 0; s2 < 2; ++s2)
            async16(Bt + (size_t)(n0 + s2 * 32 + srow) * 1024 + k0 + schnk,
                    &Bs[(s2 * 32 + w * 8) * 64]);
        __syncthreads();
        #pragma unroll
        for (int half = 0; half < 2; ++half) {
            const int rp = ((quad + 4 * half) ^ rkey) * 8;
            short8 a[2], b[4];
            #pragma unroll
            for (int rt = 0; rt < 2; ++rt)
                a[rt] = *(const short8*)&As[(mq + rt * 16 + L15) * 64 + rp];
            #pragma unroll
            for (int ct = 0; ct < 4; ++ct)
                b[ct] = *(const short8*)&Bs[(ct * 16 + L15) * 64 + rp];
            #pragma unroll
            for (int rt = 0; rt < 2; ++rt)
                #pragma unroll
                for (int ct = 0; ct < 4; ++ct)
                    acc[rt][ct] = __builtin_amdgcn_mfma_f32_16x16x32_bf16(
                        a[rt], b[ct], acc[rt][ct], 0, 0, 0);
        }
    }
    #pragma unroll
    for (int rt = 0; rt < 2; ++rt)
        #pragma unroll
        for (int g = 0; g < 4; ++g) {
            int m = m0 + mq + rt * 16 + quad * 4 + g;
            #pragma unroll
            for (int ct = 0; ct < 4; ++ct)
                C[(size_t)m * DMODEL + n0 + ct * 16 + L15] = f2bf(acc[rt][ct][g]);
        }
}

// ---------------------------------------------------------------------------
// MFMA flash attention (R12 configuration — best measured, 68 VGPR):
// static-max softmax via fused exp2 (p = 2^((AC+BD)*0.125*log2e); scores
// bounded, masked -1e30 -> 0 exactly), row-sum by MFMA with ones B-operand.
// One 64-row q-tile per block, LPT order, dbuf K/V staging, R from global,
// Pbuf[4][16][136] window scratch (write at ct*16, gather at +C offset).
// ---------------------------------------------------------------------------
__global__ __launch_bounds__(256) void attn_mfma(const short* __restrict__ Qw,
                                                 const short* __restrict__ Qr,
                                                 const short* __restrict__ Kg,
                                                 const short* __restrict__ Vt,
                                                 const short* __restrict__ RK,
                                                 short* __restrict__ ATT)
{
    __shared__ short Ks[2][64 * 64];       // 16KB
    __shared__ short Vts[2][64 * 64];      // 16KB
    __shared__ short Pbuf[4][16][136];     // 17KB: window P + prob scratch

    const int tid  = threadIdx.x;
    const int w    = tid >> 6;
    const int lane = tid & 63;
    const int L15  = lane & 15;
    const int quad = lane >> 4;
    const int bh   = blockIdx.x;
    const int it   = 15 - (int)blockIdx.y;     // LPT: heavy tiles first
    const int h    = bh & (NHEAD - 1);
    const int b    = bh >> 4;
    const int C    = 63 - 16 * w;
    const float c1 = 0.1803368801f;            // 0.125 * log2(e)

    const short* Kbh = Kg + (size_t)bh * SEQ * DHEAD;
    const short* Vbh = Vt + (size_t)bh * DHEAD * SEQ;
    const short* Rh  = RK + (size_t)h * SEQ * DHEAD;

    const int srow  = w * 8 + (lane >> 3);
    const int schnk = ((lane & 7) ^ (lane >> 3)) * 8;
    const int rp0 = ((quad)     ^ (L15 & 7)) * 8;
    const int rp1 = ((quad + 4) ^ (L15 & 7)) * 8;

    short8 vone;
    #pragma unroll
    for (int i = 0; i < 8; ++i) vone[i] = (short)0x3F80;   // bf16 1.0

    // persistent Q fragments (A-operand): row = L15, k = quad*8 + elem
    short8 qwf[2], qrf[2];
    {
        const short* qb = Qw + ((size_t)bh * SEQ + it * 64 + w * 16 + L15) * DHEAD + quad * 8;
        qwf[0] = *(const short8*)qb;
        qwf[1] = *(const short8*)(qb + 32);
        const short* qc = Qr + ((size_t)bh * SEQ + it * 64 + w * 16 + L15) * DHEAD + quad * 8;
        qrf[0] = *(const short8*)qc;
        qrf[1] = *(const short8*)(qc + 32);
    }

    f32x4 O[4], Ol;
    #pragma unroll
    for (int c = 0; c < 4; ++c) { O[c] = (f32x4){0.f, 0.f, 0.f, 0.f}; }
    Ol = (f32x4){0.f, 0.f, 0.f, 0.f};

    // preload stage jt=0 into buf 0
    #pragma unroll
    for (int q = 0; q < 2; ++q) {
        int rr = q * 32 + srow;
        async16(Kbh + (size_t)rr * DHEAD + schnk, &Ks[0][(q * 32 + w * 8) * 64]);
        async16(Vbh + (size_t)rr * SEQ + schnk,   &Vts[0][(q * 32 + w * 8) * 64]);
    }

    for (int jt = 0; jt <= it; ++jt) {
        const int buf = jt & 1;
        const int j0  = jt * 64;
        const int rel0 = 960 + 64 * (jt - it);

        __syncthreads();   // stage(jt) landed; buf^1 free

        // ---- R window fragments direct from global (issued first) ----
        short8 rb0[5], rb1[5];
        #pragma unroll
        for (int cp = 0; cp < 5; ++cp) {
            int ct  = (3 - w) + cp;
            int rel = rel0 + ct * 16 + L15;
            rel = (rel > SEQ - 1) ? (SEQ - 1) : rel;  // clamped rows feed only masked S
            const short* rp = Rh + (size_t)rel * DHEAD + quad * 8;
            rb0[cp] = *(const short8*)rp;
            rb1[cp] = *(const short8*)(rp + 32);
        }

        if (jt < it) {
            const int j0n = j0 + 64;
            #pragma unroll
            for (int q = 0; q < 2; ++q) {
                int rr = q * 32 + srow;
                async16(Kbh + (size_t)(j0n + rr) * DHEAD + schnk,
                        &Ks[buf ^ 1][(q * 32 + w * 8) * 64]);
                async16(Vbh + (size_t)rr * SEQ + j0n + schnk,
                        &Vts[buf ^ 1][(q * 32 + w * 8) * 64]);
            }
        }

        // ---- AC = Qw . K^T ----
        f32x4 S[4];
        #pragma unroll
        for (int ct = 0; ct < 4; ++ct) {
            short8 b0 = *(const short8*)&Ks[buf][(ct * 16 + L15) * 64 + rp0];
            short8 b1 = *(const short8*)&Ks[buf][(ct * 16 + L15) * 64 + rp1];
            f32x4 acc = (f32x4){0.f, 0.f, 0.f, 0.f};
            acc = __builtin_amdgcn_mfma_f32_16x16x32_bf16(qwf[0], b0, acc, 0, 0, 0);
            acc = __builtin_amdgcn_mfma_f32_16x16x32_bf16(qwf[1], b1, acc, 0, 0, 0);
            S[ct] = acc;
        }

        // ---- BD window matmul (wave w: window tiles 3-w .. 7-w) ----
        #pragma unroll
        for (int cp = 0; cp < 5; ++cp) {
            int ct = (3 - w) + cp;
            f32x4 p = (f32x4){0.f, 0.f, 0.f, 0.f};
            p = __builtin_amdgcn_mfma_f32_16x16x32_bf16(qrf[0], rb0[cp], p, 0, 0, 0);
            p = __builtin_amdgcn_mfma_f32_16x16x32_bf16(qrf[1], rb1[cp], p, 0, 0, 0);
            #pragma unroll
            for (int g = 0; g < 4; ++g)
                Pbuf[w][quad * 4 + g][ct * 16 + L15] = f2bf(p[g]);
        }

        // ---- gather rel-shift; raw sum kept (scale folded into exp2) ----
        #pragma unroll
        for (int ct = 0; ct < 4; ++ct) {
            #pragma unroll
            for (int g = 0; g < 4; ++g) {
                int r = quad * 4 + g;
                int t = ct * 16 + L15 - r + C;
                S[ct][g] += bf2f(Pbuf[w][r][t]);
            }
        }
        if (jt == it) {
            #pragma unroll
            for (int ct = 0; ct < 4; ++ct)
                #pragma unroll
                for (int g = 0; g < 4; ++g) {
                    int i = it * 64 + w * 16 + quad * 4 + g;
                    int j = j0 + ct * 16 + L15;
                    if (j > i) S[ct][g] = -1e30f;
                }
        }

        // ---- static-max softmax: p = 2^(S * 0.125*log2e), to bf16 LDS ----
        #pragma unroll
        for (int ct = 0; ct < 4; ++ct)
            #pragma unroll
            for (int g = 0; g < 4; ++g)
                Pbuf[w][quad * 4 + g][ct * 16 + L15] =
                    f2bf(__builtin_amdgcn_exp2f(S[ct][g] * c1));
        short8 pa0 = *(const short8*)&Pbuf[w][L15][quad * 8];
        short8 pa1 = *(const short8*)&Pbuf[w][L15][32 + quad * 8];

        // ---- O += P . V ;  l += P . 1 ----
        #pragma unroll
        for (int ct = 0; ct < 4; ++ct) {
            short8 v0 = *(const short8*)&Vts[buf][(ct * 16 + L15) * 64 + rp0];
            short8 v1 = *(const short8*)&Vts[buf][(ct * 16 + L15) * 64 + rp1];
            O[ct] = __builtin_amdgcn_mfma_f32_16x16x32_bf16(pa0, v0, O[ct], 0, 0, 0);
            O[ct] = __builtin_amdgcn_mfma_f32_16x16x32_bf16(pa1, v1, O[ct], 0, 0, 0);
        }
        Ol = __builtin_amdgcn_mfma_f32_16x16x32_bf16(pa0, vone, Ol, 0, 0, 0);
        Ol = __builtin_amdgcn_mfma_f32_16x16x32_bf16(pa1, vone, Ol, 0, 0, 0);
    }

    // ---- epilogue: normalize by MFMA row-sum l, write ATT bf16 ----
    #pragma unroll
    for (int g = 0; g < 4; ++g) {
        float inv = 1.0f / Ol[g];
        int i = it * 64 + w * 16 + quad * 4 + g;
        #pragma unroll
        for (int ct = 0; ct < 4; ++ct)
            ATT[((size_t)i * BSZW + b) * DMODEL + h * DHEAD + ct * 16 + L15] =
                f2bf(O[ct][g] * inv);
    }
}

// ---------------------------------------------------------------------------
// Residual + LayerNorm -> f32 out. One block per row; AO read as bf16.
// ---------------------------------------------------------------------------
__global__ __launch_bounds__(256) void ln_kernel(const float* __restrict__ w,
                                                 const short* __restrict__ AOb,
                                                 const float* __restrict__ g,
                                                 const float* __restrict__ bb,
                                                 float* __restrict__ out)
{
    __shared__ float red[256];
    __shared__ float sh_mu, sh_rs;
    const int m = blockIdx.x;
    const int tid = threadIdx.x;
    const int j0 = tid * 4;
    float4 xw = *(const float4*)(w + (size_t)m * DMODEL + j0);
    short4v xa = *(const short4v*)(AOb + (size_t)m * DMODEL + j0);
    float x[4] = {xw.x + bf2f(xa[0]), xw.y + bf2f(xa[1]),
                  xw.z + bf2f(xa[2]), xw.w + bf2f(xa[3])};
    red[tid] = x[0] + x[1] + x[2] + x[3];
    __syncthreads();
    for (int st = 128; st > 0; st >>= 1) {
        if (tid < st) red[tid] += red[tid + st];
        __syncthreads();
    }
    if (tid == 0) sh_mu = red[0] * (1.0f / DMODEL);
    __syncthreads();
    const float mu = sh_mu;
    float v = 0.0f;
    #pragma unroll
    for (int k = 0; k < 4; ++k) { float d = x[k] - mu; v += d * d; }
    red[tid] = v;
    __syncthreads();
    for (int st = 128; st > 0; st >>= 1) {
        if (tid < st) red[tid] += red[tid + st];
        __syncthreads();
    }
    if (tid == 0) sh_rs = rsqrtf(red[0] * (1.0f / DMODEL) + 1e-5f);
    __syncthreads();
    const float rs = sh_rs;
    float4 g4 = *(const float4*)(g + j0);
    float4 b4 = *(const float4*)(bb + j0);
    float4 o4;
    o4.x = (x[0] - mu) * rs * g4.x + b4.x;
    o4.y = (x[1] - mu) * rs * g4.y + b4.y;
    o4.z = (x[2] - mu) * rs * g4.z + b4.z;
    o4.w = (x[3] - mu) * rs * g4.w + b4.w;
    *(float4*)(out + (size_t)m * DMODEL + j0) = o4;
}

extern "C" void kernel_launch(void* const* d_in, const int* in_sizes, int n_in,
                              void* d_out, int out_size, void* d_ws, size_t ws_size,
                              hipStream_t stream)
{
    (void)in_sizes; (void)n_in; (void)out_size; (void)ws_size;
    const float* w     = (const float*)d_in[0];
    const float* r     = (const float*)d_in[1];
    // d_in[2] attn_mask: causal triu(k=1), hardcoded in attn_mfma
    const float* qkv_w = (const float*)d_in[3];
    const float* r_w   = (const float*)d_in[4];
    const float* o_w   = (const float*)d_in[5];
    const float* rrb   = (const float*)d_in[6];  // r_r_bias (BD path)
    const float* rwb   = (const float*)d_in[7];  // r_w_bias (AC path)
    const float* ln_g  = (const float*)d_in[8];
    const float* ln_b  = (const float*)d_in[9];
    float* out = (float*)d_out;

    const size_t M1 = 1024 * 1024;
    short* Wb   = (short*)d_ws;        // 4M shorts
    short* QKVt = Wb   + 4 * M1;       // 3M
    short* rb   = QKVt + 3 * M1;       // 1M
    short* RWt  = rb   + 1 * M1;       // 1M
    short* OWt  = RWt  + 1 * M1;       // 1M
    short* Qwb  = OWt  + 1 * M1;       // 4M
    short* Qrb  = Qwb  + 4 * M1;       // 4M
    short* Kb   = Qrb  + 4 * M1;       // 4M
    short* Vb   = Kb   + 4 * M1;       // 4M
    short* Vtb  = Vb   + 4 * M1;       // 4M
    short* RKb  = Vtb  + 4 * M1;       // 1M   -> total 31M shorts = 62 MB
    short* ATTb = Vb;                  // alias: Vb dead after vtrans
    short* AOb  = Kb;                  // alias: Kb dead after attn_mfma

    prep_all<<<dim3(QKVN / 32, DMODEL / 32, 4), 256, 0, stream>>>(
        w, r, qkv_w, r_w, o_w, Wb, rb, QKVt, RWt, OWt);

    qkv_rk_mfma<<<dim3(24, 35), 256, 0, stream>>>(Wb, QKVt, rb, RWt,
                                                  rwb, rrb,
                                                  Qwb, Qrb, Kb, Vb, RKb);
    vtrans<<<dim3(SEQ / 32, DHEAD / 32, BSZW * NHEAD), 256, 0, stream>>>(Vb, Vtb);
    attn_mfma<<<dim3(BSZW * NHEAD, 16), 256, 0, stream>>>(Qwb, Qrb, Kb, Vtb, RKb, ATTb);
    oproj_mfma<<<dim3(16, 32), 256, 0, stream>>>(ATTb, OWt, AOb);
    ln_kernel<<<MROWS, 256, 0, stream>>>(w, AOb, ln_g, ln_b, out);
}